// Round 15
// baseline (242.578 us; speedup 1.0000x reference)
//
#include <hip/hip_runtime.h>
#include <hip/hip_bf16.h>
#include <stdint.h>

// TemporalAttention for MI355X (gfx950). B=16, N=256, T=128, H=128.
// R13: R12 (5-GEMM algebraic fusion, staged pre-swizzled weights, no-max softmax)
//      restructured to 4 waves x 32 rows/wave (two 16-row strips per wave):
//      every LDS fragment read (weights, Y, V2^T) feeds TWO MFMAs -> LDS bytes
//      through the read pipe halve (the dominant pipe, ~60% of wall).
//      256 threads, __launch_bounds__(256,2): 2 blocks/CU (LDS 72.8KB), VGPR
//      cap ~256 so doubled accumulators fit without spill.

typedef __bf16 bf16;
typedef __bf16 bf16x4 __attribute__((ext_vector_type(4)));
typedef __bf16 bf16x8 __attribute__((ext_vector_type(8)));
typedef float  f32x4  __attribute__((ext_vector_type(4)));

#define MFMA16(a, b, c) __builtin_amdgcn_mfma_f32_16x16x32_bf16((a), (b), (c), 0, 0, 0)

__device__ __forceinline__ int allBytesNonzero(unsigned v) {
    return ((v - 0x01010101u) & ~v & 0x80808080u) == 0u;
}

__device__ __forceinline__ bf16x8 cvt8(const float* p) {
    float4 f0 = *reinterpret_cast<const float4*>(p);
    float4 f1 = *reinterpret_cast<const float4*>(p + 4);
    bf16x8 r;
    r[0] = (bf16)f0.x; r[1] = (bf16)f0.y; r[2] = (bf16)f0.z; r[3] = (bf16)f0.w;
    r[4] = (bf16)f1.x; r[5] = (bf16)f1.y; r[6] = (bf16)f1.z; r[7] = (bf16)f1.w;
    return r;
}

// branchless erf-GELU, A&S 7.1.26 (|err| < 1.5e-7)
__device__ __forceinline__ float gelu_erf(float v) {
    float x  = v * 0.70710678118654752f;
    float ax = fabsf(x);
    float t  = __builtin_amdgcn_rcpf(1.0f + 0.3275911f * ax);
    float p  = ((((1.061405429f * t - 1.453152027f) * t + 1.421413741f) * t
                 - 0.284496736f) * t + 0.254829592f) * t;
    float er = 1.0f - p * __expf(-ax * ax);
    er = copysignf(er, x);
    return 0.5f * v * (1.0f + er);
}

// ---- merged prep: blocks [0,128) W1T; [128,256) G+vvec; [256,384) N+bias2;
//      [384,640) npart. Weight tables written PRE-SWIZZLED:
//      dst[row*128 + (k ^ ((row&15)<<3))]. ----
__global__ void prep_all(const float* __restrict__ W_in, const float* __restrict__ Wq,
                         const float* __restrict__ Wk, const float* __restrict__ bq,
                         const float* __restrict__ Wv, const float* __restrict__ Wo,
                         const float* __restrict__ bv, const float* __restrict__ bo,
                         const int* __restrict__ nf, const float* __restrict__ E_node,
                         bf16* __restrict__ wsW, bf16* __restrict__ mstore,
                         bf16* __restrict__ nstore, float* __restrict__ vvec,
                         float* __restrict__ bias2, float* __restrict__ npart)
{
    const int blk = blockIdx.x, t = threadIdx.x;
    if (blk < 128) {
        wsW[blk * 128 + (t ^ ((blk & 15) << 3))] = (bf16)W_in[t * 128 + blk];
    } else if (blk < 256) {
        const int a = blk - 128;
        __shared__ float wqa[128];
        wqa[t] = Wq[a * 128 + t];
        __syncthreads();
        float acc = 0.f;
        for (int k = 0; k < 128; ++k) acc += wqa[k] * Wk[t * 128 + k];
        mstore[a * 128 + (t ^ ((a & 15) << 3))] = (bf16)acc;  // G[a][b]
        if (a == 0) {
            float av = 0.f;
            for (int j = 0; j < 128; ++j) av += Wk[t * 128 + j] * bq[j];
            vvec[t] = av;                                     // v = Wk bq
        }
    } else if (blk < 384) {
        const int h = blk - 256;
        __shared__ float wvh[128];
        wvh[t] = Wv[h * 128 + t];
        __syncthreads();
        float acc = 0.f;
        for (int j = 0; j < 128; ++j) acc += wvh[j] * Wo[j * 128 + t];
        nstore[t * 128 + (h ^ ((t & 15) << 3))] = (bf16)acc;  // N^T[h2][h]
        if (h == 0) {
            float b2 = 0.f;
            for (int j = 0; j < 128; ++j) b2 += bv[j] * Wo[j * 128 + t];
            bias2[t] = b2 + bo[t];                            // Wo^T bv + bo
        }
    } else {
        const int n = blk - 384;
        int node = nf[n];
        const float* e = E_node + node * 128;
        float acc = 0.f;
        for (int k = 0; k < 128; ++k) acc += e[k] * W_in[(256 + k) * 128 + t];
        npart[n * 128 + t] = acc;
    }
}

// ---- prep_bias: biasT[b][t][h] (h fastest); trig once per block ----
__global__ void prep_bias(const float* __restrict__ ex, const float* __restrict__ W_t,
                          const float* __restrict__ b_t, const float* __restrict__ W_in,
                          const float* __restrict__ b_in, float* __restrict__ biasT)
{
    const int bt = blockIdx.x;          // b*128 + t
    const int t = bt & 127;
    const int h = threadIdx.x;
    __shared__ float te[128];
    __shared__ float sn[64], cs[64];
    float v = b_t[h];
    const float* exr = ex + (size_t)bt * 32;
    for (int d = 0; d < 32; ++d) v += exr[d] * W_t[d * 128 + h];
    te[h] = v;
    if (h < 64) {
        const float ninv = -9.210340371976184f / 128.0f;   // -ln(10000)/H
        float div = expf((float)(2 * h) * ninv);
        float ang = (float)t * div;
        sn[h] = sinf(ang);
        cs[h] = cosf(ang);
    }
    __syncthreads();
    float acc = b_in[h];
    for (int j = 0; j < 64; ++j)
        acc += sn[j] * W_in[(2 * j) * 128 + h] + cs[j] * W_in[(2 * j + 1) * 128 + h];
    for (int k = 0; k < 128; ++k) acc += te[k] * W_in[(128 + k) * 128 + h];
    biasT[(size_t)bt * 128 + h] = acc;   // [b][t][h]
}

// ---- main fused kernel: 1 block per (b,n), 4 waves, wave w owns rows [32w,32w+32)
//      as two 16-row strips; every fragment read feeds 2 MFMAs. ----
// MFMA 16x16x32: A row=lane&15,k=(lane>>4)*8+j; B col=lane&15,k=(lane>>4)*8+j;
// C/D col=lane&15, row=(lane>>4)*4+reg.
#define STAGE_ISSUE(SRC)                                                        \
    {                                                                           \
        _Pragma("unroll")                                                       \
        for (int i = 0; i < 8; ++i)                                             \
            stg[i] = *reinterpret_cast<const bf16x8*>((SRC) + (tid + i * 256) * 8); \
    }
#define STAGE_WRITE()                                                           \
    {                                                                           \
        _Pragma("unroll")                                                       \
        for (int i = 0; i < 8; ++i)                                             \
            *reinterpret_cast<bf16x8*>(&sW[(tid + i * 256) * 8]) = stg[i];      \
    }

__global__ __launch_bounds__(256, 2) void fused_main(
    const float* __restrict__ xf, const unsigned char* __restrict__ mask,
    const bf16* __restrict__ wsW, const float* __restrict__ biasT,
    const float* __restrict__ npart, const float* __restrict__ vvec,
    const float* __restrict__ bias2, float* __restrict__ out)
{
    const bf16* W1T = wsW;
    const bf16* Mst = wsW + 16384;
    const bf16* Nst = wsW + 32768;

    __shared__ bf16 sW[16384];       // single staged-weight slot (XOR-swizzled)
    __shared__ bf16 sKV[128][136];   // Y[t][a] -> V2^T[h2][t]
    __shared__ bf16 sT[4][16][40];   // per-wave chunked transpose patch
    __shared__ __align__(16) float sTm[128];
    __shared__ __align__(16) float sWt[128];

    const int bn = blockIdx.x;
    const int b  = bn >> 8;
    const int n  = bn & 255;
    const int tid  = (int)threadIdx.x;
    const int w    = tid >> 6;      // 0..3
    const int lane = tid & 63;
    const int c = lane & 15;
    const int g = lane >> 4;
    const int s0 = w << 5;          // 32 rows per wave (two 16-row strips)

    const f32x4 FZ = {0.f, 0.f, 0.f, 0.f};
    bf16x8 stg[8];
    bf16* patch = &sT[w][0][0];     // wave-private [16][40]

    // ---- t_mask[t] = all(mask[b,n,t,:]) ----
    if (tid < 128) {
        const uint4* mp = reinterpret_cast<const uint4*>(mask + ((size_t)bn * 128 + tid) * 128);
        int ok = 1;
        #pragma unroll
        for (int i = 0; i < 8; ++i) {
            uint4 u = mp[i];
            ok &= allBytesNonzero(u.x) & allBytesNonzero(u.y)
                & allBytesNonzero(u.z) & allBytesNonzero(u.w);
        }
        sTm[tid] = ok ? 1.0f : 0.0f;
    }

    // ---- stage W1 -> sW; prefetch xf fragments for both strips ----
    STAGE_ISSUE(W1T);
    bf16x8 af[2][4];
    {
        const float* xfb = xf + (size_t)bn * 16384;
        #pragma unroll
        for (int st = 0; st < 2; ++st)
            #pragma unroll
            for (int kk = 0; kk < 4; ++kk)
                af[st][kk] = cvt8(xfb + (s0 + st * 16 + c) * 128 + kk * 32 + g * 8);
    }
    STAGE_WRITE();
    __syncthreads();                      // #1: sW=W1, sTm

    // ---------- G1 (swapped): X = gelu(xf@W1 + biasT + npart); transpose -> xb regs ----------
    STAGE_ISSUE(Mst);                     // G loads fly during G1
    bf16x8 xb[2][4];
    {
        const float* biasB = biasT + (size_t)b * 16384;   // [t][h]
        const float* npRow = npart + n * 128;
        f32x4 acc[2][8];
        #pragma unroll
        for (int st = 0; st < 2; ++st)
            #pragma unroll
            for (int ht = 0; ht < 8; ++ht) acc[st][ht] = FZ;
        __builtin_amdgcn_s_setprio(1);
        #pragma unroll
        for (int kk = 0; kk < 4; ++kk) {
            const int k0 = kk * 32 + g * 8;
            #pragma unroll
            for (int ht = 0; ht < 8; ++ht) {
                bf16x8 aw = *reinterpret_cast<const bf16x8*>(
                    &sW[(ht * 16 + c) * 128 + (k0 ^ ((c & 15) << 3))]);
                acc[0][ht] = MFMA16(aw, af[0][kk], acc[0][ht]);
                acc[1][ht] = MFMA16(aw, af[1][kk], acc[1][ht]);
            }
        }
        __builtin_amdgcn_s_setprio(0);
        #pragma unroll
        for (int st = 0; st < 2; ++st) {
            const int t = s0 + st * 16 + c;
            bf16x4 pk[8];
            #pragma unroll
            for (int ht = 0; ht < 8; ++ht) {
                const int hb = ht * 16 + g * 4;
                const float4 bb  = *reinterpret_cast<const float4*>(biasB + t * 128 + hb);
                const float4 np4 = *reinterpret_cast<const float4*>(npRow + hb);
                pk[ht][0] = (bf16)gelu_erf(acc[st][ht][0] + bb.x + np4.x);
                pk[ht][1] = (bf16)gelu_erf(acc[st][ht][1] + bb.y + np4.y);
                pk[ht][2] = (bf16)gelu_erf(acc[st][ht][2] + bb.z + np4.z);
                pk[ht][3] = (bf16)gelu_erf(acc[st][ht][3] + bb.w + np4.w);
            }
            // chunked transpose (wave-private; same-wave write->read)
            #pragma unroll
            for (int kk = 0; kk < 4; ++kk) {
                *reinterpret_cast<bf16x4*>(patch + c * 40 + g * 4)      = pk[2 * kk];
                *reinterpret_cast<bf16x4*>(patch + c * 40 + 16 + g * 4) = pk[2 * kk + 1];
                xb[st][kk] = *reinterpret_cast<const bf16x8*>(patch + c * 40 + g * 8);
            }
        }
    }
    __syncthreads();                      // #2: all waves done reading sW=W1

    STAGE_WRITE();                        // G -> sW (linear: pre-swizzled source)
    __syncthreads();                      // #3: sW=G published

    // ---------- Y = X @ G^T (swapped) -> sKV[t][a]; w[t] = X[t].v -> sWt ----------
    STAGE_ISSUE(Nst);                     // N loads fly during Y
    {
        f32x4 acc[2][8];
        #pragma unroll
        for (int st = 0; st < 2; ++st)
            #pragma unroll
            for (int ht = 0; ht < 8; ++ht) acc[st][ht] = FZ;
        __builtin_amdgcn_s_setprio(1);
        #pragma unroll
        for (int kk = 0; kk < 4; ++kk) {
            const int k0 = kk * 32 + g * 8;
            #pragma unroll
            for (int ht = 0; ht < 8; ++ht) {
                bf16x8 aw = *reinterpret_cast<const bf16x8*>(
                    &sW[(ht * 16 + c) * 128 + (k0 ^ ((c & 15) << 3))]);
                acc[0][ht] = MFMA16(aw, xb[0][kk], acc[0][ht]);
                acc[1][ht] = MFMA16(aw, xb[1][kk], acc[1][ht]);
            }
        }
        __builtin_amdgcn_s_setprio(0);
        #pragma unroll
        for (int st = 0; st < 2; ++st) {
            const int t = s0 + st * 16 + c;
            #pragma unroll
            for (int ht = 0; ht < 8; ++ht) {
                bf16x4 pk;
                #pragma unroll
                for (int r = 0; r < 4; ++r) pk[r] = (bf16)acc[st][ht][r];
                *reinterpret_cast<bf16x4*>(&sKV[t][ht * 16 + g * 4]) = pk;
            }
            // w[t] = dot(X[t], v)
            float wd = 0.f;
            #pragma unroll
            for (int kk = 0; kk < 4; ++kk) {
                const float4 vA = *reinterpret_cast<const float4*>(vvec + kk * 32 + g * 8);
                const float4 vB = *reinterpret_cast<const float4*>(vvec + kk * 32 + g * 8 + 4);
                wd += (float)xb[st][kk][0] * vA.x + (float)xb[st][kk][1] * vA.y
                    + (float)xb[st][kk][2] * vA.z + (float)xb[st][kk][3] * vA.w
                    + (float)xb[st][kk][4] * vB.x + (float)xb[st][kk][5] * vB.y
                    + (float)xb[st][kk][6] * vB.z + (float)xb[st][kk][7] * vB.w;
            }
            wd += __shfl_xor(wd, 16);
            wd += __shfl_xor(wd, 32);
            if (g == 0) sWt[t] = wd;
        }
    }
    __syncthreads();                      // #4: Y + sWt published; G reads done

    STAGE_WRITE();                        // N -> sW (linear)
    __syncthreads();                      // #5: sW=N published

    const float rs = 0.08838834764831845f;  // 1/sqrt(128)
    float invl[2] = {1.f, 1.f};
    bf16x8 xp[2][4];
    bf16x4 vpk[2][8];

    // ---------- V2 = X @ N (before scores: frees acc regs early) ----------
    {
        f32x4 acc[2][8];
        #pragma unroll
        for (int st = 0; st < 2; ++st)
            #pragma unroll
            for (int ct = 0; ct < 8; ++ct) acc[st][ct] = FZ;
        __builtin_amdgcn_s_setprio(1);
        #pragma unroll
        for (int kk = 0; kk < 4; ++kk) {
            const int k0 = kk * 32 + g * 8;
            #pragma unroll
            for (int ct = 0; ct < 8; ++ct) {
                bf16x8 bw = *reinterpret_cast<const bf16x8*>(
                    &sW[(ct * 16 + c) * 128 + (k0 ^ ((c & 15) << 3))]);
                acc[0][ct] = MFMA16(xb[0][kk], bw, acc[0][ct]);
                acc[1][ct] = MFMA16(xb[1][kk], bw, acc[1][ct]);
            }
        }
        __builtin_amdgcn_s_setprio(0);
        #pragma unroll
        for (int st = 0; st < 2; ++st)
            #pragma unroll
            for (int ct = 0; ct < 8; ++ct)
                #pragma unroll
                for (int r = 0; r < 4; ++r)
                    vpk[st][ct][r] = (bf16)acc[st][ct][r];
    }

    // ---------- scores^T[t][s] = Y·X^T + w[t] ; softmax (no max-sub) ; P -> xp ----------
    {
        f32x4 sc[2][8];
        #pragma unroll
        for (int st = 0; st < 2; ++st)
            #pragma unroll
            for (int rt = 0; rt < 8; ++rt) sc[st][rt] = FZ;
        __builtin_amdgcn_s_setprio(1);
        #pragma unroll
        for (int kk = 0; kk < 4; ++kk) {
            const int k0 = kk * 32 + g * 8;
            #pragma unroll
            for (int rt = 0; rt < 8; ++rt) {
                bf16x8 ay = *reinterpret_cast<const bf16x8*>(&sKV[rt * 16 + c][k0]);
                sc[0][rt] = MFMA16(ay, xb[0][kk], sc[0][rt]);
                sc[1][rt] = MFMA16(ay, xb[1][kk], sc[1][rt]);
            }
        }
        __builtin_amdgcn_s_setprio(0);

        #pragma unroll
        for (int st = 0; st < 2; ++st) {
            float ls = 0.f, wsum = 0.f;
            #pragma unroll
            for (int rt = 0; rt < 8; ++rt) {
                const float4 wt4 = *reinterpret_cast<const float4*>(&sWt[rt * 16 + g * 4]);
                const float4 tm4 = *reinterpret_cast<const float4*>(&sTm[rt * 16 + g * 4]);
                const float wtr[4] = {wt4.x, wt4.y, wt4.z, wt4.w};
                const float tmr[4] = {tm4.x, tm4.y, tm4.z, tm4.w};
                #pragma unroll
                for (int r = 0; r < 4; ++r) {
                    float p = __expf((sc[st][rt][r] + wtr[r]) * rs);
                    sc[st][rt][r] = p;
                    ls += p;
                    wsum += p * tmr[r];
                }
            }
            ls   += __shfl_xor(ls, 16);   ls   += __shfl_xor(ls, 32);
            wsum += __shfl_xor(wsum, 16); wsum += __shfl_xor(wsum, 32);
            invl[st] = __builtin_amdgcn_rcpf(ls);
            if (g == 0)
                out[(size_t)67108864 + (size_t)bn * 128 + s0 + st * 16 + c]
                    = 1.0f - wsum * invl[st];
            // P chunked transpose (wave-private) -> xp
            bf16x4 pkP[8];
            #pragma unroll
            for (int rt = 0; rt < 8; ++rt)
                #pragma unroll
                for (int r = 0; r < 4; ++r) pkP[rt][r] = (bf16)sc[st][rt][r];
            #pragma unroll
            for (int kk = 0; kk < 4; ++kk) {
                *reinterpret_cast<bf16x4*>(patch + c * 40 + g * 4)      = pkP[2 * kk];
                *reinterpret_cast<bf16x4*>(patch + c * 40 + 16 + g * 4) = pkP[2 * kk + 1];
                xp[st][kk] = *reinterpret_cast<const bf16x8*>(patch + c * 40 + g * 8);
            }
        }
    }
    __syncthreads();                      // #6: all waves done reading sKV(Y)

    // ---------- V2 (regs) -> sKV as V2^T[h2][t] ----------
    {
        #pragma unroll
        for (int st = 0; st < 2; ++st)
            #pragma unroll
            for (int ct = 0; ct < 8; ++ct)
                *reinterpret_cast<bf16x4*>(&sKV[ct * 16 + c][s0 + st * 16 + g * 4]) = vpk[st][ct];
    }
    __syncthreads();                      // #7: V2^T published

    // ---------- out^T[h2][s] = V2^T·P * invl + bias2 ; store f32 ----------
    {
        f32x4 rc[2][8];
        #pragma unroll
        for (int st = 0; st < 2; ++st)
            #pragma unroll
            for (int rt = 0; rt < 8; ++rt) rc[st][rt] = FZ;
        __builtin_amdgcn_s_setprio(1);
        #pragma unroll
        for (int kk = 0; kk < 4; ++kk) {
            const int k0 = kk * 32 + g * 8;
            #pragma unroll
            for (int rt = 0; rt < 8; ++rt) {
                bf16x8 avf = *reinterpret_cast<const bf16x8*>(&sKV[rt * 16 + c][k0]);
                rc[0][rt] = MFMA16(avf, xp[0][kk], rc[0][rt]);
                rc[1][rt] = MFMA16(avf, xp[1][kk], rc[1][rt]);
            }
        }
        __builtin_amdgcn_s_setprio(0);
        #pragma unroll
        for (int st = 0; st < 2; ++st) {
            float* outb = out + (size_t)bn * 16384 + (size_t)(s0 + st * 16 + c) * 128;
            const float il = invl[st];
            #pragma unroll
            for (int rt = 0; rt < 8; ++rt) {
                const int hb = rt * 16 + g * 4;
                const float4 b2 = *reinterpret_cast<const float4*>(bias2 + hb);
                float4 v;
                v.x = rc[st][rt][0] * il + b2.x;
                v.y = rc[st][rt][1] * il + b2.y;
                v.z = rc[st][rt][2] * il + b2.z;
                v.w = rc[st][rt][3] * il + b2.w;
                *reinterpret_cast<float4*>(outb + hb) = v;
            }
        }
    }
}

extern "C" void kernel_launch(void* const* d_in, const int* in_sizes, int n_in,
                              void* d_out, int out_size, void* d_ws, size_t ws_size,
                              hipStream_t stream)
{
    (void)in_sizes; (void)n_in; (void)out_size; (void)ws_size;
    const float* xf     = (const float*)d_in[0];
    const float* ex     = (const float*)d_in[1];
    const int*   nf     = (const int*)d_in[2];
    const unsigned char* mask = (const unsigned char*)d_in[3];
    const float* W_in   = (const float*)d_in[4];
    const float* b_in   = (const float*)d_in[5];
    const float* W_t    = (const float*)d_in[6];
    const float* b_t    = (const float*)d_in[7];
    const float* E_node = (const float*)d_in[8];
    const float* W_q    = (const float*)d_in[9];
    const float* b_q    = (const float*)d_in[10];
    const float* W_k    = (const float*)d_in[11];
    const float* b_k    = (const float*)d_in[12];
    const float* W_v    = (const float*)d_in[13];
    const float* b_v    = (const float*)d_in[14];
    const float* W_o    = (const float*)d_in[15];
    const float* b_o    = (const float*)d_in[16];
    (void)b_k;
    float* out = (float*)d_out;

    // ws layout (bytes):
    //   [0, 32768)          W1T bf16 [h][k]  (pre-swizzled)
    //   [32768, 65536)      mstore bf16 G[a][b]  (pre-swizzled)
    //   [65536, 98304)      nstore bf16 N^T[h2][h]  (pre-swizzled)
    //   [98304, 1146880)    biasT f32 [16][128][128] (h fastest)
    //   [1146880, 1277952)  npart f32 [256][128]
    //   [1277952, 1278464)  vvec f32 [128]
    //   [1278464, 1278976)  bias2 f32 [128]
    bf16*  wsW    = (bf16*)d_ws;
    bf16*  mstore = wsW + 16384;
    bf16*  nstore = wsW + 32768;
    float* biasT  = (float*)((char*)d_ws + 98304);
    float* npart  = (float*)((char*)d_ws + 1146880);
    float* vvec   = (float*)((char*)d_ws + 1277952);
    float* bias2  = (float*)((char*)d_ws + 1278464);

    prep_all<<<640, 128, 0, stream>>>(W_in, W_q, W_k, b_q, W_v, W_o, b_v, b_o,
                                      nf, E_node, wsW, mstore, nstore,
                                      vvec, bias2, npart);
    prep_bias<<<2048, 128, 0, stream>>>(ex, W_t, b_t, W_in, b_in, biasT);
    fused_main<<<4096, 256, 0, stream>>>(xf, mask, wsW, biasT, npart,
                                         vvec, bias2, out);
}

// Round 16
// 225.034 us; speedup vs baseline: 1.0780x; 1.0780x over previous
//
#include <hip/hip_runtime.h>
#include <hip/hip_bf16.h>
#include <stdint.h>

// TemporalAttention for MI355X (gfx950). B=16, N=256, T=128, H=128.
// R14: R12 base (8 waves x 16 rows, 5-GEMM algebraic fusion, no-max softmax,
//      pre-swizzled weights) restructured to TWO 32KB LDS slots (A/B):
//        b#1: A=W1, B=G (both staged up front, zero extra serialization)
//        G1 reads A | b#2 | Y reads B(G), writes Y->A (swizzled) | b#3 |
//        scores reads A(Y), N->B ds_write fills MFMA->softmax gap | b#4 |
//        V2 reads B(N), V2^T->A | b#5 | PV reads A.
//      Barriers 7 -> 5; LDS 77 -> 75KB (2 blocks/CU); wave count unchanged.

typedef __bf16 bf16;
typedef __bf16 bf16x4 __attribute__((ext_vector_type(4)));
typedef __bf16 bf16x8 __attribute__((ext_vector_type(8)));
typedef float  f32x4  __attribute__((ext_vector_type(4)));

#define MFMA16(a, b, c) __builtin_amdgcn_mfma_f32_16x16x32_bf16((a), (b), (c), 0, 0, 0)

__device__ __forceinline__ int allBytesNonzero(unsigned v) {
    return ((v - 0x01010101u) & ~v & 0x80808080u) == 0u;
}

__device__ __forceinline__ bf16x8 cvt8(const float* p) {
    float4 f0 = *reinterpret_cast<const float4*>(p);
    float4 f1 = *reinterpret_cast<const float4*>(p + 4);
    bf16x8 r;
    r[0] = (bf16)f0.x; r[1] = (bf16)f0.y; r[2] = (bf16)f0.z; r[3] = (bf16)f0.w;
    r[4] = (bf16)f1.x; r[5] = (bf16)f1.y; r[6] = (bf16)f1.z; r[7] = (bf16)f1.w;
    return r;
}

// branchless erf-GELU, A&S 7.1.26 (|err| < 1.5e-7)
__device__ __forceinline__ float gelu_erf(float v) {
    float x  = v * 0.70710678118654752f;
    float ax = fabsf(x);
    float t  = __builtin_amdgcn_rcpf(1.0f + 0.3275911f * ax);
    float p  = ((((1.061405429f * t - 1.453152027f) * t + 1.421413741f) * t
                 - 0.284496736f) * t + 0.254829592f) * t;
    float er = 1.0f - p * __expf(-ax * ax);
    er = copysignf(er, x);
    return 0.5f * v * (1.0f + er);
}

// ---- merged prep: blocks [0,128) W1T; [128,256) G+vvec; [256,384) N+bias2;
//      [384,640) npart. Weight tables written PRE-SWIZZLED:
//      dst[row*128 + (k ^ ((row&15)<<3))]. ----
__global__ void prep_all(const float* __restrict__ W_in, const float* __restrict__ Wq,
                         const float* __restrict__ Wk, const float* __restrict__ bq,
                         const float* __restrict__ Wv, const float* __restrict__ Wo,
                         const float* __restrict__ bv, const float* __restrict__ bo,
                         const int* __restrict__ nf, const float* __restrict__ E_node,
                         bf16* __restrict__ wsW, bf16* __restrict__ mstore,
                         bf16* __restrict__ nstore, float* __restrict__ vvec,
                         float* __restrict__ bias2, float* __restrict__ npart)
{
    const int blk = blockIdx.x, t = threadIdx.x;
    if (blk < 128) {
        wsW[blk * 128 + (t ^ ((blk & 15) << 3))] = (bf16)W_in[t * 128 + blk];
    } else if (blk < 256) {
        const int a = blk - 128;
        __shared__ float wqa[128];
        wqa[t] = Wq[a * 128 + t];
        __syncthreads();
        float acc = 0.f;
        for (int k = 0; k < 128; ++k) acc += wqa[k] * Wk[t * 128 + k];
        mstore[a * 128 + (t ^ ((a & 15) << 3))] = (bf16)acc;  // G[a][b]
        if (a == 0) {
            float av = 0.f;
            for (int j = 0; j < 128; ++j) av += Wk[t * 128 + j] * bq[j];
            vvec[t] = av;                                     // v = Wk bq
        }
    } else if (blk < 384) {
        const int h = blk - 256;
        __shared__ float wvh[128];
        wvh[t] = Wv[h * 128 + t];
        __syncthreads();
        float acc = 0.f;
        for (int j = 0; j < 128; ++j) acc += wvh[j] * Wo[j * 128 + t];
        nstore[t * 128 + (h ^ ((t & 15) << 3))] = (bf16)acc;  // N^T[h2][h]
        if (h == 0) {
            float b2 = 0.f;
            for (int j = 0; j < 128; ++j) b2 += bv[j] * Wo[j * 128 + t];
            bias2[t] = b2 + bo[t];                            // Wo^T bv + bo
        }
    } else {
        const int n = blk - 384;
        int node = nf[n];
        const float* e = E_node + node * 128;
        float acc = 0.f;
        for (int k = 0; k < 128; ++k) acc += e[k] * W_in[(256 + k) * 128 + t];
        npart[n * 128 + t] = acc;
    }
}

// ---- prep_bias: biasT[b][t][h] (h fastest); trig once per block ----
__global__ void prep_bias(const float* __restrict__ ex, const float* __restrict__ W_t,
                          const float* __restrict__ b_t, const float* __restrict__ W_in,
                          const float* __restrict__ b_in, float* __restrict__ biasT)
{
    const int bt = blockIdx.x;          // b*128 + t
    const int t = bt & 127;
    const int h = threadIdx.x;
    __shared__ float te[128];
    __shared__ float sn[64], cs[64];
    float v = b_t[h];
    const float* exr = ex + (size_t)bt * 32;
    for (int d = 0; d < 32; ++d) v += exr[d] * W_t[d * 128 + h];
    te[h] = v;
    if (h < 64) {
        const float ninv = -9.210340371976184f / 128.0f;   // -ln(10000)/H
        float div = expf((float)(2 * h) * ninv);
        float ang = (float)t * div;
        sn[h] = sinf(ang);
        cs[h] = cosf(ang);
    }
    __syncthreads();
    float acc = b_in[h];
    for (int j = 0; j < 64; ++j)
        acc += sn[j] * W_in[(2 * j) * 128 + h] + cs[j] * W_in[(2 * j + 1) * 128 + h];
    for (int k = 0; k < 128; ++k) acc += te[k] * W_in[(128 + k) * 128 + h];
    biasT[(size_t)bt * 128 + h] = acc;   // [b][t][h]
}

// ---- main fused kernel: 1 block per (b,n), 8 waves, wave w owns rows [16w,16w+16) ----
// MFMA 16x16x32: A row=lane&15,k=(lane>>4)*8+j; B col=lane&15,k=(lane>>4)*8+j;
// C/D col=lane&15, row=(lane>>4)*4+reg.
// All slot-A/B contents use the XOR layout: elem(row,col) at row*128 + (col ^ ((row&15)<<3)).
#define STAGE_ISSUE(REGS, SRC)                                                  \
    {                                                                           \
        _Pragma("unroll")                                                       \
        for (int i = 0; i < 4; ++i)                                             \
            REGS[i] = *reinterpret_cast<const bf16x8*>((SRC) + (tid + i * 512) * 8); \
    }
#define STAGE_WRITE(REGS, DST)                                                  \
    {                                                                           \
        _Pragma("unroll")                                                       \
        for (int i = 0; i < 4; ++i)                                             \
            *reinterpret_cast<bf16x8*>(&(DST)[(tid + i * 512) * 8]) = REGS[i];  \
    }

__global__ __launch_bounds__(512, 4) void fused_main(
    const float* __restrict__ xf, const unsigned char* __restrict__ mask,
    const bf16* __restrict__ wsW, const float* __restrict__ biasT,
    const float* __restrict__ npart, const float* __restrict__ vvec,
    const float* __restrict__ bias2, float* __restrict__ out)
{
    const bf16* W1T = wsW;
    const bf16* Mst = wsW + 16384;
    const bf16* Nst = wsW + 32768;

    __shared__ bf16 sA[16384];       // slot A: W1 -> Y -> V2^T (XOR layout)
    __shared__ bf16 sB[16384];       // slot B: G -> N          (XOR layout)
    __shared__ bf16 sT[8][16][40];   // per-wave chunked transpose patch
    __shared__ __align__(16) float sTm[128];
    __shared__ __align__(16) float sWt[128];

    const int bn = blockIdx.x;
    const int b  = bn >> 8;
    const int n  = bn & 255;
    const int tid  = (int)threadIdx.x;
    const int w    = tid >> 6;      // 0..7
    const int lane = tid & 63;
    const int c = lane & 15;
    const int g = lane >> 4;
    const int s0 = w << 4;          // 16 rows per wave

    const f32x4 FZ = {0.f, 0.f, 0.f, 0.f};
    bf16x8 stgA[4], stgB[4];
    bf16* patch = &sT[w][0][0];     // wave-private [16][40]
    const int cx = c << 3;          // XOR key for this lane's row group

    // ---- t_mask[t] = all(mask[b,n,t,:]) ----
    if (tid < 128) {
        const uint4* mp = reinterpret_cast<const uint4*>(mask + ((size_t)bn * 128 + tid) * 128);
        int ok = 1;
        #pragma unroll
        for (int i = 0; i < 8; ++i) {
            uint4 u = mp[i];
            ok &= allBytesNonzero(u.x) & allBytesNonzero(u.y)
                & allBytesNonzero(u.z) & allBytesNonzero(u.w);
        }
        sTm[tid] = ok ? 1.0f : 0.0f;
    }

    // ---- stage W1 -> A and G -> B up front; prefetch xf fragments ----
    STAGE_ISSUE(stgA, W1T);
    STAGE_ISSUE(stgB, Mst);
    bf16x8 af[4];
    {
        const float* xfb = xf + (size_t)bn * 16384;
        #pragma unroll
        for (int kk = 0; kk < 4; ++kk)
            af[kk] = cvt8(xfb + (s0 + c) * 128 + kk * 32 + g * 8);
    }
    STAGE_WRITE(stgA, sA);
    STAGE_WRITE(stgB, sB);
    __syncthreads();                      // #1: A=W1, B=G, sTm

    // ---------- G1 (swapped): X = gelu(xf@W1 + biasT + npart); transpose -> xb regs ----------
    bf16x8 xb[4];
    {
        const float* biasB = biasT + (size_t)b * 16384;   // [t][h]
        const float* npRow = npart + n * 128;
        const int t = s0 + c;
        float bbr[8][4];
        #pragma unroll
        for (int ht = 0; ht < 8; ++ht) {
            const int hb = ht * 16 + g * 4;
            const float4 bb  = *reinterpret_cast<const float4*>(biasB + t * 128 + hb);
            const float4 np4 = *reinterpret_cast<const float4*>(npRow + hb);
            bbr[ht][0] = bb.x + np4.x; bbr[ht][1] = bb.y + np4.y;
            bbr[ht][2] = bb.z + np4.z; bbr[ht][3] = bb.w + np4.w;
        }
        f32x4 acc[8];
        #pragma unroll
        for (int ht = 0; ht < 8; ++ht) acc[ht] = FZ;
        __builtin_amdgcn_s_setprio(1);
        #pragma unroll
        for (int kk = 0; kk < 4; ++kk) {
            const int k0 = kk * 32 + g * 8;
            #pragma unroll
            for (int ht = 0; ht < 8; ++ht) {
                bf16x8 aw = *reinterpret_cast<const bf16x8*>(
                    &sA[(ht * 16 + c) * 128 + (k0 ^ cx)]);
                acc[ht] = MFMA16(aw, af[kk], acc[ht]);
            }
        }
        __builtin_amdgcn_s_setprio(0);
        bf16x4 pk[8];
        #pragma unroll
        for (int ht = 0; ht < 8; ++ht)
            #pragma unroll
            for (int r = 0; r < 4; ++r)
                pk[ht][r] = (bf16)gelu_erf(acc[ht][r] + bbr[ht][r]);
        // chunked transpose (wave-private; same-wave write->read)
        #pragma unroll
        for (int kk = 0; kk < 4; ++kk) {
            *reinterpret_cast<bf16x4*>(patch + c * 40 + g * 4)      = pk[2 * kk];
            *reinterpret_cast<bf16x4*>(patch + c * 40 + 16 + g * 4) = pk[2 * kk + 1];
            xb[kk] = *reinterpret_cast<const bf16x8*>(patch + c * 40 + g * 8);
        }
    }
    __syncthreads();                      // #2: all waves done reading A(W1)

    // ---------- Y = X @ G^T (swapped) -> A (swizzled); w[t] = X[t].v -> sWt ----------
    STAGE_ISSUE(stgA, Nst);               // N loads fly during Y
    {
        f32x4 acc[8];
        #pragma unroll
        for (int ht = 0; ht < 8; ++ht) acc[ht] = FZ;
        __builtin_amdgcn_s_setprio(1);
        #pragma unroll
        for (int kk = 0; kk < 4; ++kk) {
            const int k0 = kk * 32 + g * 8;
            #pragma unroll
            for (int ht = 0; ht < 8; ++ht) {
                bf16x8 aw = *reinterpret_cast<const bf16x8*>(
                    &sB[(ht * 16 + c) * 128 + (k0 ^ cx)]);
                acc[ht] = MFMA16(aw, xb[kk], acc[ht]);
            }
        }
        __builtin_amdgcn_s_setprio(0);
        const int t = s0 + c;
        #pragma unroll
        for (int ht = 0; ht < 8; ++ht) {
            bf16x4 pk;
            #pragma unroll
            for (int r = 0; r < 4; ++r) pk[r] = (bf16)acc[ht][r];
            *reinterpret_cast<bf16x4*>(&sA[t * 128 + ((ht * 16 + g * 4) ^ cx)]) = pk;
        }
        // w[t] = dot(X[t], v)
        float wd = 0.f;
        #pragma unroll
        for (int kk = 0; kk < 4; ++kk) {
            const float4 vA = *reinterpret_cast<const float4*>(vvec + kk * 32 + g * 8);
            const float4 vB = *reinterpret_cast<const float4*>(vvec + kk * 32 + g * 8 + 4);
            wd += (float)xb[kk][0] * vA.x + (float)xb[kk][1] * vA.y
                + (float)xb[kk][2] * vA.z + (float)xb[kk][3] * vA.w
                + (float)xb[kk][4] * vB.x + (float)xb[kk][5] * vB.y
                + (float)xb[kk][6] * vB.z + (float)xb[kk][7] * vB.w;
        }
        wd += __shfl_xor(wd, 16);
        wd += __shfl_xor(wd, 32);
        if (g == 0) sWt[t] = wd;
    }
    __syncthreads();                      // #3: Y + sWt published; B(G) reads done

    const float rs = 0.08838834764831845f;  // 1/sqrt(128)
    float invl = 1.f;
    bf16x8 xp[4];

    // ---------- scores-MFMA (reads A=Y) -> N->B write (gap filler) -> softmax -> P ----------
    {
        f32x4 sc[8];
        #pragma unroll
        for (int rt = 0; rt < 8; ++rt) sc[rt] = FZ;
        __builtin_amdgcn_s_setprio(1);
        #pragma unroll
        for (int kk = 0; kk < 4; ++kk) {
            const int k0 = kk * 32 + g * 8;
            #pragma unroll
            for (int rt = 0; rt < 8; ++rt) {
                bf16x8 ay = *reinterpret_cast<const bf16x8*>(
                    &sA[(rt * 16 + c) * 128 + (k0 ^ cx)]);
                sc[rt] = MFMA16(ay, xb[kk], sc[rt]);
            }
        }
        __builtin_amdgcn_s_setprio(0);

        STAGE_WRITE(stgA, sB);            // N -> B; ds_writes overlap MFMA drain

        // ---- softmax over t, NO max subtraction ----
        float ls = 0.f, wsum = 0.f;
        #pragma unroll
        for (int rt = 0; rt < 8; ++rt) {
            const float4 wt4 = *reinterpret_cast<const float4*>(&sWt[rt * 16 + g * 4]);
            const float4 tm4 = *reinterpret_cast<const float4*>(&sTm[rt * 16 + g * 4]);
            const float wtr[4] = {wt4.x, wt4.y, wt4.z, wt4.w};
            const float tmr[4] = {tm4.x, tm4.y, tm4.z, tm4.w};
            #pragma unroll
            for (int r = 0; r < 4; ++r) {
                float p = __expf((sc[rt][r] + wtr[r]) * rs);
                sc[rt][r] = p;
                ls += p;
                wsum += p * tmr[r];
            }
        }
        ls   += __shfl_xor(ls, 16);   ls   += __shfl_xor(ls, 32);
        wsum += __shfl_xor(wsum, 16); wsum += __shfl_xor(wsum, 32);
        invl = __builtin_amdgcn_rcpf(ls);
        if (g == 0)
            out[(size_t)67108864 + (size_t)bn * 128 + s0 + c] = 1.0f - wsum * invl;
        // P chunked transpose (wave-private) -> xp
        bf16x4 pkP[8];
        #pragma unroll
        for (int rt = 0; rt < 8; ++rt)
            #pragma unroll
            for (int r = 0; r < 4; ++r) pkP[rt][r] = (bf16)sc[rt][r];
        #pragma unroll
        for (int kk = 0; kk < 4; ++kk) {
            *reinterpret_cast<bf16x4*>(patch + c * 40 + g * 4)      = pkP[2 * kk];
            *reinterpret_cast<bf16x4*>(patch + c * 40 + 16 + g * 4) = pkP[2 * kk + 1];
            xp[kk] = *reinterpret_cast<const bf16x8*>(patch + c * 40 + g * 8);
        }
    }
    __syncthreads();                      // #4: N published; A(Y) reads done

    // ---------- V2 = X @ N (reads B) -> V2^T -> A (swizzled) ----------
    {
        f32x4 acc[8];
        #pragma unroll
        for (int ct = 0; ct < 8; ++ct) acc[ct] = FZ;
        __builtin_amdgcn_s_setprio(1);
        #pragma unroll
        for (int kk = 0; kk < 4; ++kk) {
            const int k0 = kk * 32 + g * 8;
            #pragma unroll
            for (int ct = 0; ct < 8; ++ct) {
                bf16x8 bw = *reinterpret_cast<const bf16x8*>(
                    &sB[(ct * 16 + c) * 128 + (k0 ^ cx)]);
                acc[ct] = MFMA16(xb[kk], bw, acc[ct]);
            }
        }
        __builtin_amdgcn_s_setprio(0);
        #pragma unroll
        for (int ct = 0; ct < 8; ++ct) {
            bf16x4 pk;
            #pragma unroll
            for (int r = 0; r < 4; ++r) pk[r] = (bf16)acc[ct][r];
            *reinterpret_cast<bf16x4*>(&sA[(ct * 16 + c) * 128 + ((s0 + g * 4) ^ cx)]) = pk;
        }
    }
    __syncthreads();                      // #5: V2^T published

    // ---------- out^T[h2][s] = V2^T·P * invl + bias2 ; store f32 ----------
    {
        f32x4 rc[8];
        #pragma unroll
        for (int rt = 0; rt < 8; ++rt) rc[rt] = FZ;
        __builtin_amdgcn_s_setprio(1);
        #pragma unroll
        for (int kk = 0; kk < 4; ++kk) {
            const int k0 = kk * 32 + g * 8;
            #pragma unroll
            for (int rt = 0; rt < 8; ++rt) {
                bf16x8 avf = *reinterpret_cast<const bf16x8*>(
                    &sA[(rt * 16 + c) * 128 + (k0 ^ cx)]);
                rc[rt] = MFMA16(avf, xp[kk], rc[rt]);
            }
        }
        __builtin_amdgcn_s_setprio(0);
        float* outb = out + (size_t)bn * 16384 + (size_t)(s0 + c) * 128;
        #pragma unroll
        for (int rt = 0; rt < 8; ++rt) {
            const int hb = rt * 16 + g * 4;
            const float4 b2 = *reinterpret_cast<const float4*>(bias2 + hb);
            float4 v;
            v.x = rc[rt][0] * invl + b2.x;
            v.y = rc[rt][1] * invl + b2.y;
            v.z = rc[rt][2] * invl + b2.z;
            v.w = rc[rt][3] * invl + b2.w;
            *reinterpret_cast<float4*>(outb + hb) = v;
        }
    }
}

extern "C" void kernel_launch(void* const* d_in, const int* in_sizes, int n_in,
                              void* d_out, int out_size, void* d_ws, size_t ws_size,
                              hipStream_t stream)
{
    (void)in_sizes; (void)n_in; (void)out_size; (void)ws_size;
    const float* xf     = (const float*)d_in[0];
    const float* ex     = (const float*)d_in[1];
    const int*   nf     = (const int*)d_in[2];
    const unsigned char* mask = (const unsigned char*)d_in[3];
    const float* W_in   = (const float*)d_in[4];
    const float* b_in   = (const float*)d_in[5];
    const float* W_t    = (const float*)d_in[6];
    const float* b_t    = (const float*)d_in[7];
    const float* E_node = (const float*)d_in[8];
    const float* W_q    = (const float*)d_in[9];
    const float* b_q    = (const float*)d_in[10];
    const float* W_k    = (const float*)d_in[11];
    const float* b_k    = (const float*)d_in[12];
    const float* W_v    = (const float*)d_in[13];
    const float* b_v    = (const float*)d_in[14];
    const float* W_o    = (const float*)d_in[15];
    const float* b_o    = (const float*)d_in[16];
    (void)b_k;
    float* out = (float*)d_out;

    // ws layout (bytes):
    //   [0, 32768)          W1T bf16 [h][k]  (pre-swizzled)
    //   [32768, 65536)      mstore bf16 G[a][b]  (pre-swizzled)
    //   [65536, 98304)      nstore bf16 N^T[h2][h]  (pre-swizzled)
    //   [98304, 1146880)    biasT f32 [16][128][128] (h fastest)
    //   [1146880, 1277952)  npart f32 [256][128]
    //   [1277952, 1278464)  vvec f32 [128]
    //   [1278464, 1278976)  bias2 f32 [128]
    bf16*  wsW    = (bf16*)d_ws;
    bf16*  mstore = wsW + 16384;
    bf16*  nstore = wsW + 32768;
    float* biasT  = (float*)((char*)d_ws + 98304);
    float* npart  = (float*)((char*)d_ws + 1146880);
    float* vvec   = (float*)((char*)d_ws + 1277952);
    float* bias2  = (float*)((char*)d_ws + 1278464);

    prep_all<<<640, 128, 0, stream>>>(W_in, W_q, W_k, b_q, W_v, W_o, b_v, b_o,
                                      nf, E_node, wsW, mstore, nstore,
                                      vvec, bias2, npart);
    prep_bias<<<2048, 128, 0, stream>>>(ex, W_t, b_t, W_in, b_in, biasT);
    fused_main<<<4096, 512, 0, stream>>>(xf, mask, wsW, biasT, npart,
                                         vvec, bias2, out);
}